// Round 22
// baseline (279.347 us; speedup 1.0000x reference)
//
#include <hip/hip_runtime.h>
#include <cfloat>
#include <math.h>

// Problem constants
#define N_TEXT  226
#define N_IMG   5400
#define N_TOKEN 5626
#define HEAD_STRIDE 31651876u   // N_TOKEN*N_TOKEN
#define TOTAL_ELEMS 126607504u  // 4 * HEAD_STRIDE
#define NA4  317869             // f4 slots in region A per head (226*5626/4)
#define NQB  57                 // aligned f4 slots covering cols [0,226) per row
#define NA_ALL (4 * NA4)        // 1271476
#define NB_ALL (4 * 5400 * NQB) // 1231200
#define TEXT_BLOCKS 289         // D1: every 8th block of grid 2314
#define GRID_D1 2314            // 2314 - floor(2314/8) = 2025 tile blocks (h0+h1)
#define GRID_D2 4941            // 2025 (h2) + 2916 (h3)

// f32(1/15): XLA rewrites divide-by-constant into multiply-by-reciprocal.
#define RCP15 0x1.111112p-4f

typedef float f32x4 __attribute__((ext_vector_type(4)));

// Locked bit-exact arithmetic (verified r9/r11/r14/r16/r20/r21, absmax=0):
//   scale = fl32(delta*fl32(1/15)); safe = scale==0?1:scale;
//   recip = fl32(1/safe); q = clip(roundeven(fl32(x*recip)),0,15);
//   out = fl32(q*scale).
__device__ __forceinline__ float fq1(float x, float recip, float scale) {
    float q = rintf(__fmul_rn(x, recip));
    q = fminf(fmaxf(q, 0.0f), 15.0f);
    return __fmul_rn(q, scale);
}

// ---------------------------------------------------------------------------
// Register-path fused tile (r16/r21-validated, byte-identical), T=1024.
// ---------------------------------------------------------------------------
template <int BW, int NB, int R>
__device__ __forceinline__ void tile_reg(const float* __restrict__ in,
                                         float* __restrict__ out,
                                         int local, int head) {
    constexpr int NQ   = BW / 4 + 1;     // 51 / 38
    constexpr int TOTQ = BW * NQ;

    const int bi = local / NB;
    const int bj = local - bi * NB;
    const unsigned base = (unsigned)head * HEAD_STRIDE
                        + (unsigned)(N_TEXT + bi * BW) * N_TOKEN
                        + (unsigned)(N_TEXT + bj * BW);
    const int tid = threadIdx.x;

    f32x4 vr[R];
    float m = 0.0f;                       // inputs are >= 0
    #pragma unroll
    for (int j = 0; j < R; ++j) {
        const int i = tid + j * 1024;
        const int r = i / NQ;
        const int k = i - r * NQ;
        const unsigned rowbase = base + (unsigned)r * N_TOKEN;
        const int s = (int)(rowbase & 3u);            // 0 or 2
        const unsigned a0 = rowbase - s + (unsigned)(k << 2);
        const bool act = (i < TOTQ) && (a0 + 4u <= TOTAL_ELEMS);
        vr[j] = act ? *(const f32x4*)(in + a0) : (f32x4){0.f, 0.f, 0.f, 0.f};
        if (act) {
            const int c0 = (k << 2) - s;
            m = fmaxf(m, (c0 >= 0 && c0 < BW)         ? vr[j].x : 0.0f);
            m = fmaxf(m, (c0 + 1 >= 0 && c0 + 1 < BW) ? vr[j].y : 0.0f);
            m = fmaxf(m, (c0 + 2 < BW)                ? vr[j].z : 0.0f);
            m = fmaxf(m, (c0 + 3 < BW)                ? vr[j].w : 0.0f);
        }
    }

    #pragma unroll
    for (int o = 32; o > 0; o >>= 1)
        m = fmaxf(m, __shfl_xor(m, o));
    __shared__ float sm[16];
    if ((tid & 63) == 0) sm[tid >> 6] = m;
    __syncthreads();
    float delta = sm[0];
    #pragma unroll
    for (int w = 1; w < 16; ++w) delta = fmaxf(delta, sm[w]);

    const float scale = __fmul_rn(delta, RCP15);
    const float safe  = (scale == 0.0f) ? 1.0f : scale;
    const float recip = __fdiv_rn(1.0f, safe);

    #pragma unroll
    for (int j = 0; j < R; ++j) {
        const int i = tid + j * 1024;
        const int r = i / NQ;
        const int k = i - r * NQ;
        const unsigned rowbase = base + (unsigned)r * N_TOKEN;
        const int s = (int)(rowbase & 3u);
        const unsigned a0 = rowbase - s + (unsigned)(k << 2);
        if (i >= TOTQ || a0 + 4u > TOTAL_ELEMS) continue;
        const int c0 = (k << 2) - s;
        f32x4 v = vr[j];
        v.x = fq1(v.x, recip, scale);
        v.y = fq1(v.y, recip, scale);
        v.z = fq1(v.z, recip, scale);
        v.w = fq1(v.w, recip, scale);
        if (c0 >= 0 && c0 + 3 < BW) {
            *(f32x4*)(out + a0) = v;
        } else {
            if (c0 >= 0 && c0 < BW)         out[a0]     = v.x;
            if (c0 + 1 >= 0 && c0 + 1 < BW) out[a0 + 1] = v.y;
            if (c0 + 2 < BW)                out[a0 + 2] = v.z;
            if (c0 + 3 < BW)                out[a0 + 3] = v.w;
        }
    }
}

// ---------------------------------------------------------------------------
// LDS-path fused tile (T=512): LDS is a software spill buffer escaping the
// 64-VGPR compiler cap (r17-r19). Each thread reads back only its own slots
// stile[j*512+tid] -> no barrier needed for the tile buffer; 64 KB LDS ->
// 2 blocks/CU co-resident, phase-offset load/store overlap.
// Masks/indexing: r20-validated at T=512 (absmax=0).
// ---------------------------------------------------------------------------
template <int BW, int NB, int HEAD, int R>
__device__ __forceinline__ void tile_lds(const float* __restrict__ in,
                                         float* __restrict__ out,
                                         f32x4* __restrict__ stile,
                                         float* __restrict__ sm,
                                         int local) {
    constexpr int NQ   = BW / 4 + 1;     // 31 / 26
    constexpr int TOTQ = BW * NQ;

    const int bi = local / NB;
    const int bj = local - bi * NB;
    const unsigned base = (unsigned)HEAD * HEAD_STRIDE
                        + (unsigned)(N_TEXT + bi * BW) * N_TOKEN
                        + (unsigned)(N_TEXT + bj * BW);
    const int tid = threadIdx.x;

    float m = 0.0f;                       // inputs are >= 0
    #pragma unroll
    for (int j = 0; j < R; ++j) {
        const int i = tid + j * 512;
        const int r = i / NQ;
        const int k = i - r * NQ;
        const unsigned rowbase = base + (unsigned)r * N_TOKEN;
        const int s = (int)(rowbase & 3u);            // 0 or 2
        const unsigned a0 = rowbase - s + (unsigned)(k << 2);
        const bool act = (i < TOTQ) && (a0 + 4u <= TOTAL_ELEMS);
        f32x4 v = act ? *(const f32x4*)(in + a0) : (f32x4){0.f, 0.f, 0.f, 0.f};
        stile[j * 512 + tid] = v;
        if (act) {
            const int c0 = (k << 2) - s;
            m = fmaxf(m, (c0 >= 0 && c0 < BW)         ? v.x : 0.0f);
            m = fmaxf(m, (c0 + 1 >= 0 && c0 + 1 < BW) ? v.y : 0.0f);
            m = fmaxf(m, (c0 + 2 < BW)                ? v.z : 0.0f);
            m = fmaxf(m, (c0 + 3 < BW)                ? v.w : 0.0f);
        }
    }

    #pragma unroll
    for (int o = 32; o > 0; o >>= 1)
        m = fmaxf(m, __shfl_xor(m, o));
    if ((tid & 63) == 0) sm[tid >> 6] = m;
    __syncthreads();
    float delta = sm[0];
    #pragma unroll
    for (int w = 1; w < 8; ++w) delta = fmaxf(delta, sm[w]);

    const float scale = __fmul_rn(delta, RCP15);
    const float safe  = (scale == 0.0f) ? 1.0f : scale;
    const float recip = __fdiv_rn(1.0f, safe);

    #pragma unroll
    for (int j = 0; j < R; ++j) {
        const int i = tid + j * 512;
        const int r = i / NQ;
        const int k = i - r * NQ;
        const unsigned rowbase = base + (unsigned)r * N_TOKEN;
        const int s = (int)(rowbase & 3u);
        const unsigned a0 = rowbase - s + (unsigned)(k << 2);
        if (i >= TOTQ || a0 + 4u > TOTAL_ELEMS) continue;
        const int c0 = (k << 2) - s;
        f32x4 v = stile[j * 512 + tid];
        v.x = fq1(v.x, recip, scale);
        v.y = fq1(v.y, recip, scale);
        v.z = fq1(v.z, recip, scale);
        v.w = fq1(v.w, recip, scale);
        if (c0 >= 0 && c0 + 3 < BW) {
            *(f32x4*)(out + a0) = v;
        } else {
            if (c0 >= 0 && c0 < BW)         out[a0]     = v.x;
            if (c0 + 1 >= 0 && c0 + 1 < BW) out[a0 + 1] = v.y;
            if (c0 + 2 < BW)                out[a0 + 2] = v.z;
            if (c0 + 3 < BW)                out[a0 + 3] = v.w;
        }
    }
}

// ---------------------------------------------------------------------------
// Text copy (grid-stride, r16/r21-validated masks), 1024-thr version.
// ---------------------------------------------------------------------------
__device__ __forceinline__ void text_copy(const float* __restrict__ in,
                                          float* __restrict__ out, int cb) {
    const int tid0   = cb * 1024 + threadIdx.x;
    const int stride = TEXT_BLOCKS * 1024;

    for (int idx = tid0; idx < NA_ALL; idx += stride) {
        const int head = idx / NA4;
        const int rem  = idx - head * NA4;
        const size_t a = (size_t)head * HEAD_STRIDE + (size_t)rem * 4;
        *(f32x4*)(out + a) = *(const f32x4*)(in + a);
    }

    for (int idx = tid0; idx < NB_ALL; idx += stride) {
        const int head = idx / (5400 * NQB);
        const int rem  = idx - head * (5400 * NQB);
        const int row  = rem / NQB;
        const int k    = rem - row * NQB;
        const unsigned rowbase = (unsigned)head * HEAD_STRIDE
                               + (unsigned)(N_TEXT + row) * N_TOKEN;
        const int s = (int)(rowbase & 3u);            // 0 or 2
        const unsigned a0 = rowbase - s + (unsigned)(k << 2);
        const int c0 = (k << 2) - s;                  // text col of elem 0
        f32x4 v = *(const f32x4*)(in + a0);
        if (c0 >= 0 && c0 + 3 < N_TEXT) {
            *(f32x4*)(out + a0) = v;
        } else {
            if (c0 >= 0 && c0 < N_TEXT)         out[a0]     = v.x;
            if (c0 + 1 >= 0 && c0 + 1 < N_TEXT) out[a0 + 1] = v.y;
            if (c0 + 2 < N_TEXT)                out[a0 + 2] = v.z;
            if (c0 + 3 < N_TEXT)                out[a0 + 3] = v.w;
        }
    }
}

// ---------------------------------------------------------------------------
// D1: heads 0+1 (register path) + all text, every-8th interleave (r21).
// ---------------------------------------------------------------------------
__global__ __launch_bounds__(1024)
void qam_d1(const float* __restrict__ in, float* __restrict__ out) {
    const int b = blockIdx.x;
    if ((b & 7) == 7) {
        text_copy(in, out, b >> 3);
        return;
    }
    const int t = b - ((b + 1) >> 3);     // tile index 0..2024
    if (t < 729) tile_reg<200, 27, 10>(in, out, t,       0);
    else         tile_reg<150, 36, 6> (in, out, t - 729, 1);
}

// ---------------------------------------------------------------------------
// D2: heads 2+3 via LDS spill path (512 thr, 64 KB -> 2 blocks/CU).
// ---------------------------------------------------------------------------
__global__ __launch_bounds__(512)
void qam_d2(const float* __restrict__ in, float* __restrict__ out) {
    __shared__ f32x4 stile[4096];         // 64 KB tile buffer
    __shared__ float sm[8];
    const int b = blockIdx.x;
    if (b < 2025) tile_lds<120, 45, 2, 8>(in, out, stile, sm, b);
    else          tile_lds<100, 54, 3, 6>(in, out, stile, sm, b - 2025);
}

extern "C" void kernel_launch(void* const* d_in, const int* in_sizes, int n_in,
                              void* d_out, int out_size, void* d_ws, size_t ws_size,
                              hipStream_t stream) {
    const float* x = (const float*)d_in[0];
    float* out     = (float*)d_out;
    qam_d1<<<GRID_D1, 1024, 0, stream>>>(x, out);
    qam_d2<<<GRID_D2,  512, 0, stream>>>(x, out);
}

// Round 23
// 250.360 us; speedup vs baseline: 1.1158x; 1.1158x over previous
//
#include <hip/hip_runtime.h>
#include <cfloat>
#include <math.h>

// Problem constants
#define N_TEXT  226
#define N_IMG   5400
#define N_TOKEN 5626
#define HEAD_STRIDE 31651876u   // N_TOKEN*N_TOKEN
#define TOTAL_ELEMS 126607504u  // 4 * HEAD_STRIDE
#define NTILE 6966              // 27^2+36^2+45^2+54^2
#define TEXT_BLOCKS 995         // interleaved: every 8th block of grid 7961
#define GRIDSZ 7961             // 7961 - floor(7961/8) = 6966 tile blocks
#define NA4  317869             // f4 slots in region A per head (226*5626/4)
#define NQB  57                 // aligned f4 slots covering cols [0,226) per row
#define NA_ALL (4 * NA4)        // 1271476
#define NB_ALL (4 * 5400 * NQB) // 1231200

// f32(1/15): XLA rewrites divide-by-constant into multiply-by-reciprocal.
#define RCP15 0x1.111112p-4f

typedef float f32x4 __attribute__((ext_vector_type(4)));

// Locked bit-exact arithmetic (verified r9/r11/r14/r16/r20/r21, absmax=0):
//   scale = fl32(delta*fl32(1/15)); safe = scale==0?1:scale;
//   recip = fl32(1/safe); q = clip(roundeven(fl32(x*recip)),0,15);
//   out = fl32(q*scale).
__device__ __forceinline__ float fq1(float x, float recip, float scale) {
    float q = rintf(__fmul_rn(x, recip));
    q = fminf(fmaxf(q, 0.0f), 15.0f);
    return __fmul_rn(q, scale);
}

// ---------------------------------------------------------------------------
// Fused per-tile quantization (r16-validated, byte-identical): load tile into
// registers via masked aligned-f4, block-reduce max, quantize, masked store.
// ---------------------------------------------------------------------------
template <int BW, int NB, int R>
__device__ __forceinline__ void tile_fused(const float* __restrict__ in,
                                           float* __restrict__ out,
                                           int local, int head) {
    constexpr int NQ   = BW / 4 + 1;     // 51 / 38 / 31 / 26
    constexpr int TOTQ = BW * NQ;

    const int bi = local / NB;
    const int bj = local - bi * NB;
    const unsigned base = (unsigned)head * HEAD_STRIDE
                        + (unsigned)(N_TEXT + bi * BW) * N_TOKEN
                        + (unsigned)(N_TEXT + bj * BW);
    const int tid = threadIdx.x;

    // ---- load + max accumulate (registers) ----
    f32x4 vr[R];
    float m = 0.0f;                       // inputs are >= 0
    #pragma unroll
    for (int j = 0; j < R; ++j) {
        const int i = tid + j * 1024;
        const int r = i / NQ;             // compile-time divisor
        const int k = i - r * NQ;
        const unsigned rowbase = base + (unsigned)r * N_TOKEN;
        const int s = (int)(rowbase & 3u);            // 0 or 2
        const unsigned a0 = rowbase - s + (unsigned)(k << 2);
        const bool act = (i < TOTQ) && (a0 + 4u <= TOTAL_ELEMS);
        vr[j] = act ? *(const f32x4*)(in + a0) : (f32x4){0.f, 0.f, 0.f, 0.f};
        if (act) {
            const int c0 = (k << 2) - s;              // tile-rel col of v.x
            m = fmaxf(m, (c0 >= 0 && c0 < BW)         ? vr[j].x : 0.0f);
            m = fmaxf(m, (c0 + 1 >= 0 && c0 + 1 < BW) ? vr[j].y : 0.0f);
            m = fmaxf(m, (c0 + 2 < BW)                ? vr[j].z : 0.0f);
            m = fmaxf(m, (c0 + 3 < BW)                ? vr[j].w : 0.0f);
        }
    }

    // ---- block reduce (16 waves) ----
    #pragma unroll
    for (int o = 32; o > 0; o >>= 1)
        m = fmaxf(m, __shfl_xor(m, o));
    __shared__ float sm[16];
    if ((tid & 63) == 0) sm[tid >> 6] = m;
    __syncthreads();
    float delta = sm[0];
    #pragma unroll
    for (int w = 1; w < 16; ++w) delta = fmaxf(delta, sm[w]);

    const float scale = __fmul_rn(delta, RCP15);
    const float safe  = (scale == 0.0f) ? 1.0f : scale;
    const float recip = __fdiv_rn(1.0f, safe);

    // ---- quantize registers + masked store ----
    #pragma unroll
    for (int j = 0; j < R; ++j) {
        const int i = tid + j * 1024;
        const int r = i / NQ;
        const int k = i - r * NQ;
        const unsigned rowbase = base + (unsigned)r * N_TOKEN;
        const int s = (int)(rowbase & 3u);
        const unsigned a0 = rowbase - s + (unsigned)(k << 2);
        if (i >= TOTQ || a0 + 4u > TOTAL_ELEMS) continue;
        const int c0 = (k << 2) - s;
        f32x4 v = vr[j];
        v.x = fq1(v.x, recip, scale);
        v.y = fq1(v.y, recip, scale);
        v.z = fq1(v.z, recip, scale);
        v.w = fq1(v.w, recip, scale);
        if (c0 >= 0 && c0 + 3 < BW) {
            *(f32x4*)(out + a0) = v;                  // interior slot
        } else {                                      // edge: per-elem mask
            if (c0 >= 0 && c0 < BW)         out[a0]     = v.x;
            if (c0 + 1 >= 0 && c0 + 1 < BW) out[a0 + 1] = v.y;
            if (c0 + 2 < BW)                out[a0 + 2] = v.z;  // c0+2>=0 always
            if (c0 + 3 < BW)                out[a0 + 3] = v.w;
        }
    }
}

// ---------------------------------------------------------------------------
// Text copy (grid-stride, r16-validated masks).
// ---------------------------------------------------------------------------
__device__ __forceinline__ void text_copy(const float* __restrict__ in,
                                          float* __restrict__ out, int cb) {
    const int tid0   = cb * 1024 + threadIdx.x;
    const int stride = TEXT_BLOCKS * 1024;

    for (int idx = tid0; idx < NA_ALL; idx += stride) {
        const int head = idx / NA4;
        const int rem  = idx - head * NA4;
        const size_t a = (size_t)head * HEAD_STRIDE + (size_t)rem * 4;
        *(f32x4*)(out + a) = *(const f32x4*)(in + a);
    }

    for (int idx = tid0; idx < NB_ALL; idx += stride) {
        const int head = idx / (5400 * NQB);
        const int rem  = idx - head * (5400 * NQB);
        const int row  = rem / NQB;
        const int k    = rem - row * NQB;
        const unsigned rowbase = (unsigned)head * HEAD_STRIDE
                               + (unsigned)(N_TEXT + row) * N_TOKEN;
        const int s = (int)(rowbase & 3u);            // 0 or 2
        const unsigned a0 = rowbase - s + (unsigned)(k << 2);
        const int c0 = (k << 2) - s;                  // text col of elem 0
        f32x4 v = *(const f32x4*)(in + a0);
        if (c0 >= 0 && c0 + 3 < N_TEXT) {
            *(f32x4*)(out + a0) = v;
        } else {
            if (c0 >= 0 && c0 < N_TEXT)         out[a0]     = v.x;
            if (c0 + 1 >= 0 && c0 + 1 < N_TEXT) out[a0 + 1] = v.y;
            if (c0 + 2 < N_TEXT)                out[a0 + 2] = v.z;
            if (c0 + 3 < N_TEXT)                out[a0 + 3] = v.w;
        }
    }
}

// ---------------------------------------------------------------------------
// Grid interleave: every 8th block (b&7==7) is a pure-streaming text-copy
// block, spread through the grid to fill tile blocks' reduce/store bubbles.
// tile_idx = b - ((b+1)>>3); text_idx = b>>3.
// ---------------------------------------------------------------------------
__global__ __launch_bounds__(1024)
void qam_fused(const float* __restrict__ in, float* __restrict__ out) {
    const int b = blockIdx.x;
    if ((b & 7) == 7) {
        text_copy(in, out, b >> 3);
        return;
    }
    const int t = b - ((b + 1) >> 3);     // tile index 0..6965
    if (t < 729)        tile_fused<200, 27, 10>(in, out, t,        0);
    else if (t < 2025)  tile_fused<150, 36, 6> (in, out, t - 729,  1);
    else if (t < 4050)  tile_fused<120, 45, 4> (in, out, t - 2025, 2);
    else                tile_fused<100, 54, 3> (in, out, t - 4050, 3);
}

extern "C" void kernel_launch(void* const* d_in, const int* in_sizes, int n_in,
                              void* d_out, int out_size, void* d_ws, size_t ws_size,
                              hipStream_t stream) {
    const float* x = (const float*)d_in[0];
    float* out     = (float*)d_out;
    qam_fused<<<GRIDSZ, 1024, 0, stream>>>(x, out);
}